// Round 1
// baseline (175.454 us; speedup 1.0000x reference)
//
#include <hip/hip_runtime.h>
#include <hip/hip_bf16.h>
#include <cstdint>
#include <cstddef>

// Problem constants (fixed by reference)
#define NE 8      // experts
#define MEt 1024  // tokens per expert
#define KD 2048   // in features
#define ND 2048   // out features
#define NG 16     // K / G  (G = 128)

// Tile config
#define BM 128
#define BN 128
#define BK 128    // one scale-group per K-step

typedef int   i32x4  __attribute__((ext_vector_type(4)));
typedef int   i32x16 __attribute__((ext_vector_type(16)));
typedef float f32x16 __attribute__((ext_vector_type(16)));

__device__ __forceinline__ unsigned pack4(int x0, int x1, int x2, int x3) {
    // pack low bytes (two's complement int8) of 4 int32 into one dword
    return (unsigned)(x0 & 0xFF) | ((unsigned)(x1 & 0xFF) << 8) |
           ((unsigned)(x2 & 0xFF) << 16) | ((unsigned)x3 << 24);
}

// Grouped W4A8 GEMM, exact int8 MFMA path with per-group float fixup.
__global__ __launch_bounds__(256, 2)
void w4a8_moe_gemm(const int* __restrict__ a_q,        // [M, K] int8 values in int32
                   const int* __restrict__ w_q,        // [E, N, K] int4 values in int32
                   const float* __restrict__ per_tok,  // [M]
                   const float* __restrict__ per_chan, // [E, N]
                   const float* __restrict__ wgs,      // [E, N, K/G]
                   float* __restrict__ out)            // [M, N] fp32
{
    __shared__ __align__(16) unsigned char As[BM * BK]; // packed int8, XOR-swizzled
    __shared__ __align__(16) unsigned char Bs[BN * BK];
    __shared__ float scs[BN];

    // XCD-chunked swizzle: 1024 blocks / 8 XCDs -> one expert per XCD (L2 locality)
    int bid = blockIdx.x;
    int b2  = (bid & 7) * 128 + (bid >> 3);
    const int e  = b2 >> 7;        // expert 0..7
    const int tm = (b2 >> 4) & 7;  // m-tile 0..7
    const int tn = b2 & 15;        // n-tile 0..15

    const int tid  = threadIdx.x;
    const int lane = tid & 63;
    const int wv   = tid >> 6;   // wave 0..3
    const int wm   = wv >> 1;    // 0..1
    const int wn   = wv & 1;     // 0..1
    const int lcol = lane & 31;
    const int lhi  = lane >> 5;

    const int* Ag = a_q + (size_t)(e * MEt + tm * BM) * KD;
    const int* Wg = w_q + ((size_t)e * ND + tn * BN) * KD;

    f32x16 facc[2][2] = {};
    const i32x16 z16 = {};  // zero seed for first MFMA of each group

    const int xorm = (lcol & 7) << 4;  // read-side XOR swizzle term

    for (int kt = 0; kt < KD / BK; ++kt) {
        // ---- stage A tile: int32 -> packed int8, swizzled LDS ----
        #pragma unroll
        for (int i = 0; i < 4; ++i) {
            int idx = tid + i * 256;
            int r   = idx >> 3;   // tile row 0..127
            int ck  = idx & 7;    // 16-elem chunk along k
            const int* gp = Ag + (size_t)r * KD + kt * BK + ck * 16;
            i32x4 v0 = *(const i32x4*)(gp);
            i32x4 v1 = *(const i32x4*)(gp + 4);
            i32x4 v2 = *(const i32x4*)(gp + 8);
            i32x4 v3 = *(const i32x4*)(gp + 12);
            i32x4 p;
            p[0] = (int)pack4(v0[0], v0[1], v0[2], v0[3]);
            p[1] = (int)pack4(v1[0], v1[1], v1[2], v1[3]);
            p[2] = (int)pack4(v2[0], v2[1], v2[2], v2[3]);
            p[3] = (int)pack4(v3[0], v3[1], v3[2], v3[3]);
            *(i32x4*)&As[r * BK + ((ck * 16) ^ ((r & 7) << 4))] = p;
        }
        // ---- stage B tile (weights) ----
        #pragma unroll
        for (int i = 0; i < 4; ++i) {
            int idx = tid + i * 256;
            int r   = idx >> 3;
            int ck  = idx & 7;
            const int* gp = Wg + (size_t)r * KD + kt * BK + ck * 16;
            i32x4 v0 = *(const i32x4*)(gp);
            i32x4 v1 = *(const i32x4*)(gp + 4);
            i32x4 v2 = *(const i32x4*)(gp + 8);
            i32x4 v3 = *(const i32x4*)(gp + 12);
            i32x4 p;
            p[0] = (int)pack4(v0[0], v0[1], v0[2], v0[3]);
            p[1] = (int)pack4(v1[0], v1[1], v1[2], v1[3]);
            p[2] = (int)pack4(v2[0], v2[1], v2[2], v2[3]);
            p[3] = (int)pack4(v3[0], v3[1], v3[2], v3[3]);
            *(i32x4*)&Bs[r * BK + ((ck * 16) ^ ((r & 7) << 4))] = p;
        }
        // ---- stage group scales for this K-step: wgs[e, n, kt] for tile cols ----
        if (tid < BN) scs[tid] = wgs[((size_t)e * ND + tn * BN + tid) * NG + kt];

        __syncthreads();

        float sc0 = scs[wn * 64 + lcol];
        float sc1 = scs[wn * 64 + 32 + lcol];

        i32x16 iacc[2][2];
        #pragma unroll
        for (int ks = 0; ks < 4; ++ks) {
            int kb = (ks * 32 + lhi * 16) ^ xorm;
            i32x4 av0 = *(const i32x4*)&As[(wm * 64 +  0 + lcol) * BK + kb];
            i32x4 av1 = *(const i32x4*)&As[(wm * 64 + 32 + lcol) * BK + kb];
            i32x4 bv0 = *(const i32x4*)&Bs[(wn * 64 +  0 + lcol) * BK + kb];
            i32x4 bv1 = *(const i32x4*)&Bs[(wn * 64 + 32 + lcol) * BK + kb];
            if (ks == 0) {
                iacc[0][0] = __builtin_amdgcn_mfma_i32_32x32x32_i8(av0, bv0, z16, 0, 0, 0);
                iacc[0][1] = __builtin_amdgcn_mfma_i32_32x32x32_i8(av0, bv1, z16, 0, 0, 0);
                iacc[1][0] = __builtin_amdgcn_mfma_i32_32x32x32_i8(av1, bv0, z16, 0, 0, 0);
                iacc[1][1] = __builtin_amdgcn_mfma_i32_32x32x32_i8(av1, bv1, z16, 0, 0, 0);
            } else {
                iacc[0][0] = __builtin_amdgcn_mfma_i32_32x32x32_i8(av0, bv0, iacc[0][0], 0, 0, 0);
                iacc[0][1] = __builtin_amdgcn_mfma_i32_32x32x32_i8(av0, bv1, iacc[0][1], 0, 0, 0);
                iacc[1][0] = __builtin_amdgcn_mfma_i32_32x32x32_i8(av1, bv0, iacc[1][0], 0, 0, 0);
                iacc[1][1] = __builtin_amdgcn_mfma_i32_32x32x32_i8(av1, bv1, iacc[1][1], 0, 0, 0);
            }
        }
        // ---- per-group float fixup: facc += (float)iacc * wgs[n, g] ----
        #pragma unroll
        for (int i = 0; i < 16; ++i) {
            facc[0][0][i] += (float)iacc[0][0][i] * sc0;
            facc[0][1][i] += (float)iacc[0][1][i] * sc1;
            facc[1][0][i] += (float)iacc[1][0][i] * sc0;
            facc[1][1][i] += (float)iacc[1][1][i] * sc1;
        }
        __syncthreads();
    }

    // ---- epilogue: apply per-token and per-channel scales, store fp32 ----
    const float* ptok  = per_tok  + e * MEt + tm * BM;
    const float* pchan = per_chan + (size_t)e * ND;
    float* og = out + (size_t)(e * MEt + tm * BM) * ND + tn * BN;

    #pragma unroll
    for (int fm = 0; fm < 2; ++fm) {
        int mb = wm * 64 + fm * 32;
        #pragma unroll
        for (int fn = 0; fn < 2; ++fn) {
            int nn = wn * 64 + fn * 32 + lcol;
            float pc = pchan[tn * BN + nn];
            #pragma unroll
            for (int rg = 0; rg < 16; ++rg) {
                int mr = mb + (rg & 3) + 8 * (rg >> 2) + 4 * lhi;
                float pt = ptok[mr];
                og[(size_t)mr * ND + nn] = facc[fm][fn][rg] * pt * pc;
            }
        }
    }
}

extern "C" void kernel_launch(void* const* d_in, const int* in_sizes, int n_in,
                              void* d_out, int out_size, void* d_ws, size_t ws_size,
                              hipStream_t stream) {
    const int*   a_q = (const int*)d_in[0];
    const int*   w_q = (const int*)d_in[1];
    const float* pt  = (const float*)d_in[2];
    const float* pc  = (const float*)d_in[3];
    const float* wg  = (const float*)d_in[4];
    float* out = (float*)d_out;

    // 8 experts * 8 m-tiles * 16 n-tiles = 1024 blocks, 256 threads (4 waves)
    w4a8_moe_gemm<<<dim3(1024), dim3(256), 0, stream>>>(a_q, w_q, pt, pc, wg, out);
}

// Round 2
// 144.310 us; speedup vs baseline: 1.2158x; 1.2158x over previous
//
#include <hip/hip_runtime.h>
#include <hip/hip_bf16.h>
#include <cstdint>
#include <cstddef>

// Problem constants (fixed by reference)
#define NE 8      // experts
#define MEt 1024  // tokens per expert
#define KD 2048   // in features
#define ND 2048   // out features
#define NG 16     // K / G  (G = 128)

// Tile config
#define BM 128
#define BN 128
#define BK 128    // one scale-group per K-step
#define NKT (KD / BK)  // 16 K-steps

typedef int   i32x4  __attribute__((ext_vector_type(4)));
typedef int   i32x16 __attribute__((ext_vector_type(16)));
typedef float f32x16 __attribute__((ext_vector_type(16)));

__device__ __forceinline__ unsigned pack4(int x0, int x1, int x2, int x3) {
    return (unsigned)(x0 & 0xFF) | ((unsigned)(x1 & 0xFF) << 8) |
           ((unsigned)(x2 & 0xFF) << 16) | ((unsigned)x3 << 24);
}

// Issue 8 global dwordx4 loads (2 j-chunks) for one half-tile slice into st[0..7].
template<int J0>
__device__ __forceinline__ void issue8(i32x4* st, const int* base, int tid) {
#pragma unroll
    for (int jj = 0; jj < 2; ++jj) {
        int idx = tid + (J0 + jj) * 256;
        int r   = idx >> 3;   // tile row
        int ck  = idx & 7;    // 16-int32 chunk along k
        const int* gp = base + (size_t)r * KD + ck * 16;
        st[jj * 4 + 0] = *(const i32x4*)(gp);
        st[jj * 4 + 1] = *(const i32x4*)(gp + 4);
        st[jj * 4 + 2] = *(const i32x4*)(gp + 8);
        st[jj * 4 + 3] = *(const i32x4*)(gp + 12);
    }
}

// Pack st[0..7] (32 int32 each holding an int8) into 2x16B swizzled LDS writes.
template<int J0>
__device__ __forceinline__ void packw8(unsigned char* lds, const i32x4* st, int tid) {
#pragma unroll
    for (int jj = 0; jj < 2; ++jj) {
        int idx = tid + (J0 + jj) * 256;
        int r   = idx >> 3;
        int ck  = idx & 7;
        const i32x4 a = st[jj * 4 + 0], b = st[jj * 4 + 1];
        const i32x4 c = st[jj * 4 + 2], d = st[jj * 4 + 3];
        i32x4 p;
        p[0] = (int)pack4(a[0], a[1], a[2], a[3]);
        p[1] = (int)pack4(b[0], b[1], b[2], b[3]);
        p[2] = (int)pack4(c[0], c[1], c[2], c[3]);
        p[3] = (int)pack4(d[0], d[1], d[2], d[3]);
        *(i32x4*)&lds[r * BK + ((ck * 16) ^ ((r & 7) << 4))] = p;
    }
}

__global__ __launch_bounds__(256, 2)
void w4a8_moe_gemm(const int* __restrict__ a_q,        // [M, K] int8 values in int32
                   const int* __restrict__ w_q,        // [E, N, K] int4 values in int32
                   const float* __restrict__ per_tok,  // [M]
                   const float* __restrict__ per_chan, // [E, N]
                   const float* __restrict__ wgs,      // [E, N, K/G]
                   float* __restrict__ out)            // [M, N] fp32
{
    __shared__ __align__(16) unsigned char As[2][BM * BK]; // packed int8, XOR-swizzled
    __shared__ __align__(16) unsigned char Bs[2][BN * BK];
    __shared__ float scs[NG][BN];  // transposed: conflict-free per-step broadcast

    // XCD-chunked swizzle: one expert per XCD (L2 locality)
    int bid = blockIdx.x;
    int b2  = (bid & 7) * 128 + (bid >> 3);
    const int e  = b2 >> 7;        // expert 0..7
    const int tm = (b2 >> 4) & 7;  // m-tile 0..7
    const int tn = b2 & 15;        // n-tile 0..15

    const int tid  = threadIdx.x;
    const int lane = tid & 63;
    const int wv   = tid >> 6;   // wave 0..3
    const int wm   = wv >> 1;    // 0..1
    const int wn   = wv & 1;     // 0..1
    const int lcol = lane & 31;
    const int lhi  = lane >> 5;

    const int* Ag = a_q + (size_t)(e * MEt + tm * BM) * KD;
    const int* Wg = w_q + ((size_t)e * ND + tn * BN) * KD;

    f32x16 facc[2][2] = {};
    const i32x16 z16 = {};
    const int xorm = (lcol & 7) << 4;

    i32x4 st[8];  // staging registers (32 VGPRs in flight)

    // ---- prologue: stage tile 0 into buffer 0, plus all group scales ----
    issue8<0>(st, Ag, tid); packw8<0>(As[0], st, tid);
    issue8<2>(st, Ag, tid); packw8<2>(As[0], st, tid);
    issue8<0>(st, Wg, tid); packw8<0>(Bs[0], st, tid);
    issue8<2>(st, Wg, tid); packw8<2>(Bs[0], st, tid);
#pragma unroll
    for (int i = 0; i < 8; ++i) {
        int idx = tid + i * 256;
        int g = idx >> 7, n = idx & 127;
        scs[g][n] = wgs[((size_t)e * ND + tn * BN + n) * NG + g];
    }
    __syncthreads();

    int c = 0;
    for (int kt = 0; kt < NKT; ++kt) {
        const bool pf = (kt + 1) < NKT;
        const int* An = Ag + (kt + 1) * BK;
        const int* Wn = Wg + (kt + 1) * BK;
        unsigned char* Anx = As[c ^ 1];
        unsigned char* Bnx = Bs[c ^ 1];
        const unsigned char* Ac = As[c];
        const unsigned char* Bc = Bs[c];

        float sc0 = scs[kt][wn * 64 + lcol];
        float sc1 = scs[kt][wn * 64 + 32 + lcol];

        i32x16 iacc[2][2];

#define KSPHASE(ks, SEED)                                                        \
        {                                                                        \
            int kb = ((ks) * 32 + lhi * 16) ^ xorm;                              \
            i32x4 av0 = *(const i32x4*)&Ac[(wm * 64 +  0 + lcol) * BK + kb];     \
            i32x4 av1 = *(const i32x4*)&Ac[(wm * 64 + 32 + lcol) * BK + kb];     \
            i32x4 bv0 = *(const i32x4*)&Bc[(wn * 64 +  0 + lcol) * BK + kb];     \
            i32x4 bv1 = *(const i32x4*)&Bc[(wn * 64 + 32 + lcol) * BK + kb];     \
            iacc[0][0] = __builtin_amdgcn_mfma_i32_32x32x32_i8(av0, bv0, SEED(0,0), 0, 0, 0); \
            iacc[0][1] = __builtin_amdgcn_mfma_i32_32x32x32_i8(av0, bv1, SEED(0,1), 0, 0, 0); \
            iacc[1][0] = __builtin_amdgcn_mfma_i32_32x32x32_i8(av1, bv0, SEED(1,0), 0, 0, 0); \
            iacc[1][1] = __builtin_amdgcn_mfma_i32_32x32x32_i8(av1, bv1, SEED(1,1), 0, 0, 0); \
        }
#define SEEDZ(i, j) z16
#define SEEDA(i, j) iacc[i][j]

        // phase 0: prefetch A half 0 || compute ks0
        if (pf) issue8<0>(st, An, tid);
        KSPHASE(0, SEEDZ)
        if (pf) packw8<0>(Anx, st, tid);

        // phase 1: prefetch A half 1 || compute ks1
        if (pf) issue8<2>(st, An, tid);
        KSPHASE(1, SEEDA)
        if (pf) packw8<2>(Anx, st, tid);

        // phase 2: prefetch B half 0 || compute ks2
        if (pf) issue8<0>(st, Wn, tid);
        KSPHASE(2, SEEDA)
        if (pf) packw8<0>(Bnx, st, tid);

        // phase 3: prefetch B half 1 || compute ks3 + fixup
        if (pf) issue8<2>(st, Wn, tid);
        KSPHASE(3, SEEDA)
#pragma unroll
        for (int i = 0; i < 16; ++i) {
            facc[0][0][i] += (float)iacc[0][0][i] * sc0;
            facc[0][1][i] += (float)iacc[0][1][i] * sc1;
            facc[1][0][i] += (float)iacc[1][0][i] * sc0;
            facc[1][1][i] += (float)iacc[1][1][i] * sc1;
        }
        if (pf) packw8<2>(Bnx, st, tid);

        __syncthreads();
        c ^= 1;
#undef KSPHASE
#undef SEEDZ
#undef SEEDA
    }

    // ---- epilogue: per-token and per-channel scales, store fp32 ----
    const float* ptok  = per_tok  + e * MEt + tm * BM;
    const float* pchan = per_chan + (size_t)e * ND;
    float* og = out + (size_t)(e * MEt + tm * BM) * ND + tn * BN;

#pragma unroll
    for (int fm = 0; fm < 2; ++fm) {
        int mb = wm * 64 + fm * 32;
#pragma unroll
        for (int fn = 0; fn < 2; ++fn) {
            int nn = wn * 64 + fn * 32 + lcol;
            float pc = pchan[tn * BN + nn];
#pragma unroll
            for (int rg = 0; rg < 16; ++rg) {
                int mr = mb + (rg & 3) + 8 * (rg >> 2) + 4 * lhi;
                float pt = ptok[mr];
                og[(size_t)mr * ND + nn] = facc[fm][fn][rg] * pt * pc;
            }
        }
    }
}

extern "C" void kernel_launch(void* const* d_in, const int* in_sizes, int n_in,
                              void* d_out, int out_size, void* d_ws, size_t ws_size,
                              hipStream_t stream) {
    const int*   a_q = (const int*)d_in[0];
    const int*   w_q = (const int*)d_in[1];
    const float* pt  = (const float*)d_in[2];
    const float* pc  = (const float*)d_in[3];
    const float* wg  = (const float*)d_in[4];
    float* out = (float*)d_out;

    // 8 experts * 8 m-tiles * 16 n-tiles = 1024 blocks, 256 threads (4 waves)
    w4a8_moe_gemm<<<dim3(1024), dim3(256), 0, stream>>>(a_q, w_q, pt, pc, wg, out);
}

// Round 3
// 107.121 us; speedup vs baseline: 1.6379x; 1.3472x over previous
//
#include <hip/hip_runtime.h>
#include <hip/hip_bf16.h>
#include <cstdint>
#include <cstddef>

// Problem constants (fixed by reference)
#define NE 8      // experts
#define MEt 1024  // tokens per expert
#define KD 2048   // in features
#define ND 2048   // out features
#define NG 16     // K / G  (G = 128)

// Tile config
#define BM 128
#define BN 128
#define BK 128    // one scale-group per K-step
#define NKT (KD / BK)  // 16 K-steps

typedef int   i32x4  __attribute__((ext_vector_type(4)));
typedef int   i32x16 __attribute__((ext_vector_type(16)));
typedef float f32x16 __attribute__((ext_vector_type(16)));

__device__ __forceinline__ unsigned pack4(int x0, int x1, int x2, int x3) {
    return (unsigned)(x0 & 0xFF) | ((unsigned)(x1 & 0xFF) << 8) |
           ((unsigned)(x2 & 0xFF) << 16) | ((unsigned)x3 << 24);
}

__device__ __forceinline__ void gl_lds16(const void* g, void* l) {
    // async global->LDS, 16B per lane; LDS dest = uniform base + lane*16
    __builtin_amdgcn_global_load_lds(
        (const __attribute__((address_space(1))) void*)g,
        (__attribute__((address_space(3))) void*)l, 16, 0, 0);
}

// ---------------- prepack: int32-held values -> int8 bytes, swizzle baked ----------------
// Stored layout: dst[row][ (col & ~127) | ((col&127) ^ ((row&7)<<4)) ] = src[row][col]
// so that linear global_load_lds staging reproduces the XOR-swizzled LDS image.
__global__ __launch_bounds__(256)
void w4a8_prepack(const int* __restrict__ a_q, const int* __restrict__ w_q,
                  unsigned char* __restrict__ a8, unsigned char* __restrict__ w8)
{
    const int ACH = (NE * MEt * KD) / 16;  // 16B chunks in A
    const int WCH = (NE * ND * KD) / 16;
    int c = blockIdx.x * 256 + threadIdx.x;
    const int* src;
    unsigned char* dst;
    int cc;
    if (c < ACH)            { src = a_q; dst = a8; cc = c; }
    else if (c < ACH + WCH) { src = w_q; dst = w8; cc = c - ACH; }
    else return;

    int elem0 = cc * 16;          // logical element index == packed byte index
    int row   = elem0 >> 11;      // K = 2048
    int col   = elem0 & 2047;
    int dcol  = (col & ~127) | ((col & 127) ^ ((row & 7) << 4));

    const int* gp = src + (size_t)elem0;
    i32x4 v0 = *(const i32x4*)(gp);
    i32x4 v1 = *(const i32x4*)(gp + 4);
    i32x4 v2 = *(const i32x4*)(gp + 8);
    i32x4 v3 = *(const i32x4*)(gp + 12);
    i32x4 p;
    p[0] = (int)pack4(v0[0], v0[1], v0[2], v0[3]);
    p[1] = (int)pack4(v1[0], v1[1], v1[2], v1[3]);
    p[2] = (int)pack4(v2[0], v2[1], v2[2], v2[3]);
    p[3] = (int)pack4(v3[0], v3[1], v3[2], v3[3]);
    *(i32x4*)(dst + (size_t)row * KD + dcol) = p;
}

// ---------------- main GEMM on prepacked int8, global_load_lds staging ----------------
// Per-wave tile stage: 4 async 16B/lane copies (8 rows x 128B each)
__device__ __forceinline__ void stage_tile(unsigned char* lds, const unsigned char* g,
                                           int wv, int lane) {
    int r  = lane >> 3;         // 0..7
    int co = (lane & 7) * 16;   // 0..112
#pragma unroll
    for (int i = 0; i < 4; ++i) {
        int rb = (wv * 4 + i) * 8;
        gl_lds16(g + (size_t)(rb + r) * KD + co, lds + (wv * 4 + i) * 1024);
    }
}

__global__ __launch_bounds__(256, 2)
void w4a8_gemm_pp(const unsigned char* __restrict__ a8,   // [M, K] int8, swizzle-baked
                  const unsigned char* __restrict__ w8,   // [E*N, K] int8, swizzle-baked
                  const float* __restrict__ per_tok,      // [M]
                  const float* __restrict__ per_chan,     // [E, N]
                  const float* __restrict__ wgs,          // [E, N, K/G]
                  float* __restrict__ out)                // [M, N] fp32
{
    __shared__ __align__(16) unsigned char As[2][BM * BK];
    __shared__ __align__(16) unsigned char Bs[2][BN * BK];
    __shared__ float scs[NG][BN];

    // XCD-chunked swizzle: one expert per XCD
    int bid = blockIdx.x;
    int b2  = (bid & 7) * 128 + (bid >> 3);
    const int e  = b2 >> 7;
    const int tm = (b2 >> 4) & 7;
    const int tn = b2 & 15;

    const int tid  = threadIdx.x;
    const int lane = tid & 63;
    const int wv   = tid >> 6;
    const int wm   = wv >> 1;
    const int wn   = wv & 1;
    const int lcol = lane & 31;
    const int lhi  = lane >> 5;

    const unsigned char* Ag = a8 + (size_t)(e * MEt + tm * BM) * KD;
    const unsigned char* Wg = w8 + ((size_t)e * ND + tn * BN) * KD;

    f32x16 facc[2][2] = {};
    const i32x16 z16 = {};
    const int xorm = (lcol & 7) << 4;

    // prologue: stage tile 0 into buffer 0 + all group scales
    stage_tile(As[0], Ag, wv, lane);
    stage_tile(Bs[0], Wg, wv, lane);
#pragma unroll
    for (int i = 0; i < 8; ++i) {
        int idx = tid + i * 256;
        int g = idx >> 7, n = idx & 127;
        scs[g][n] = wgs[((size_t)e * ND + tn * BN + n) * NG + g];
    }
    __syncthreads();

    int c = 0;
    for (int kt = 0; kt < NKT; ++kt) {
        // issue next-tile async staging first (overlaps with compute below)
        if (kt + 1 < NKT) {
            stage_tile(As[c ^ 1], Ag + (kt + 1) * BK, wv, lane);
            stage_tile(Bs[c ^ 1], Wg + (kt + 1) * BK, wv, lane);
        }
        const unsigned char* Ac = As[c];
        const unsigned char* Bc = Bs[c];
        float sc0 = scs[kt][wn * 64 + lcol];
        float sc1 = scs[kt][wn * 64 + 32 + lcol];

        i32x16 iacc[2][2];
#pragma unroll
        for (int ks = 0; ks < 4; ++ks) {
            int kb = (ks * 32 + lhi * 16) ^ xorm;
            i32x4 av0 = *(const i32x4*)&Ac[(wm * 64 +  0 + lcol) * BK + kb];
            i32x4 av1 = *(const i32x4*)&Ac[(wm * 64 + 32 + lcol) * BK + kb];
            i32x4 bv0 = *(const i32x4*)&Bc[(wn * 64 +  0 + lcol) * BK + kb];
            i32x4 bv1 = *(const i32x4*)&Bc[(wn * 64 + 32 + lcol) * BK + kb];
            if (ks == 0) {
                iacc[0][0] = __builtin_amdgcn_mfma_i32_32x32x32_i8(av0, bv0, z16, 0, 0, 0);
                iacc[0][1] = __builtin_amdgcn_mfma_i32_32x32x32_i8(av0, bv1, z16, 0, 0, 0);
                iacc[1][0] = __builtin_amdgcn_mfma_i32_32x32x32_i8(av1, bv0, z16, 0, 0, 0);
                iacc[1][1] = __builtin_amdgcn_mfma_i32_32x32x32_i8(av1, bv1, z16, 0, 0, 0);
            } else {
                iacc[0][0] = __builtin_amdgcn_mfma_i32_32x32x32_i8(av0, bv0, iacc[0][0], 0, 0, 0);
                iacc[0][1] = __builtin_amdgcn_mfma_i32_32x32x32_i8(av0, bv1, iacc[0][1], 0, 0, 0);
                iacc[1][0] = __builtin_amdgcn_mfma_i32_32x32x32_i8(av1, bv0, iacc[1][0], 0, 0, 0);
                iacc[1][1] = __builtin_amdgcn_mfma_i32_32x32x32_i8(av1, bv1, iacc[1][1], 0, 0, 0);
            }
        }
#pragma unroll
        for (int i = 0; i < 16; ++i) {
            facc[0][0][i] += (float)iacc[0][0][i] * sc0;
            facc[0][1][i] += (float)iacc[0][1][i] * sc1;
            facc[1][0][i] += (float)iacc[1][0][i] * sc0;
            facc[1][1][i] += (float)iacc[1][1][i] * sc1;
        }
        __syncthreads();
        c ^= 1;
    }

    // epilogue
    const float* ptok  = per_tok  + e * MEt + tm * BM;
    const float* pchan = per_chan + (size_t)e * ND;
    float* og = out + (size_t)(e * MEt + tm * BM) * ND + tn * BN;
#pragma unroll
    for (int fm = 0; fm < 2; ++fm) {
        int mb = wm * 64 + fm * 32;
#pragma unroll
        for (int fn = 0; fn < 2; ++fn) {
            int nn = wn * 64 + fn * 32 + lcol;
            float pc = pchan[tn * BN + nn];
#pragma unroll
            for (int rg = 0; rg < 16; ++rg) {
                int mr = mb + (rg & 3) + 8 * (rg >> 2) + 4 * lhi;
                float pt = ptok[mr];
                og[(size_t)mr * ND + nn] = facc[fm][fn][rg] * pt * pc;
            }
        }
    }
}

// ---------------- fallback: R2 fused kernel (if ws too small) ----------------
template<int J0>
__device__ __forceinline__ void issue8(i32x4* st, const int* base, int tid) {
#pragma unroll
    for (int jj = 0; jj < 2; ++jj) {
        int idx = tid + (J0 + jj) * 256;
        int r   = idx >> 3;
        int ck  = idx & 7;
        const int* gp = base + (size_t)r * KD + ck * 16;
        st[jj * 4 + 0] = *(const i32x4*)(gp);
        st[jj * 4 + 1] = *(const i32x4*)(gp + 4);
        st[jj * 4 + 2] = *(const i32x4*)(gp + 8);
        st[jj * 4 + 3] = *(const i32x4*)(gp + 12);
    }
}
template<int J0>
__device__ __forceinline__ void packw8(unsigned char* lds, const i32x4* st, int tid) {
#pragma unroll
    for (int jj = 0; jj < 2; ++jj) {
        int idx = tid + (J0 + jj) * 256;
        int r   = idx >> 3;
        int ck  = idx & 7;
        const i32x4 a = st[jj * 4 + 0], b = st[jj * 4 + 1];
        const i32x4 c = st[jj * 4 + 2], d = st[jj * 4 + 3];
        i32x4 p;
        p[0] = (int)pack4(a[0], a[1], a[2], a[3]);
        p[1] = (int)pack4(b[0], b[1], b[2], b[3]);
        p[2] = (int)pack4(c[0], c[1], c[2], c[3]);
        p[3] = (int)pack4(d[0], d[1], d[2], d[3]);
        *(i32x4*)&lds[r * BK + ((ck * 16) ^ ((r & 7) << 4))] = p;
    }
}

__global__ __launch_bounds__(256, 2)
void w4a8_moe_gemm_fused(const int* __restrict__ a_q, const int* __restrict__ w_q,
                         const float* __restrict__ per_tok, const float* __restrict__ per_chan,
                         const float* __restrict__ wgs, float* __restrict__ out)
{
    __shared__ __align__(16) unsigned char As[2][BM * BK];
    __shared__ __align__(16) unsigned char Bs[2][BN * BK];
    __shared__ float scs[NG][BN];

    int bid = blockIdx.x;
    int b2  = (bid & 7) * 128 + (bid >> 3);
    const int e  = b2 >> 7;
    const int tm = (b2 >> 4) & 7;
    const int tn = b2 & 15;

    const int tid  = threadIdx.x;
    const int lane = tid & 63;
    const int wv   = tid >> 6;
    const int wm   = wv >> 1;
    const int wn   = wv & 1;
    const int lcol = lane & 31;
    const int lhi  = lane >> 5;

    const int* Ag = a_q + (size_t)(e * MEt + tm * BM) * KD;
    const int* Wg = w_q + ((size_t)e * ND + tn * BN) * KD;

    f32x16 facc[2][2] = {};
    const i32x16 z16 = {};
    const int xorm = (lcol & 7) << 4;
    i32x4 st[8];

    issue8<0>(st, Ag, tid); packw8<0>(As[0], st, tid);
    issue8<2>(st, Ag, tid); packw8<2>(As[0], st, tid);
    issue8<0>(st, Wg, tid); packw8<0>(Bs[0], st, tid);
    issue8<2>(st, Wg, tid); packw8<2>(Bs[0], st, tid);
#pragma unroll
    for (int i = 0; i < 8; ++i) {
        int idx = tid + i * 256;
        int g = idx >> 7, n = idx & 127;
        scs[g][n] = wgs[((size_t)e * ND + tn * BN + n) * NG + g];
    }
    __syncthreads();

    int c = 0;
    for (int kt = 0; kt < NKT; ++kt) {
        const bool pf = (kt + 1) < NKT;
        const int* An = Ag + (kt + 1) * BK;
        const int* Wn = Wg + (kt + 1) * BK;
        unsigned char* Anx = As[c ^ 1];
        unsigned char* Bnx = Bs[c ^ 1];
        const unsigned char* Ac = As[c];
        const unsigned char* Bc = Bs[c];
        float sc0 = scs[kt][wn * 64 + lcol];
        float sc1 = scs[kt][wn * 64 + 32 + lcol];
        i32x16 iacc[2][2];

#define KSPHASE(ks, SEED)                                                        \
        {                                                                        \
            int kb = ((ks) * 32 + lhi * 16) ^ xorm;                              \
            i32x4 av0 = *(const i32x4*)&Ac[(wm * 64 +  0 + lcol) * BK + kb];     \
            i32x4 av1 = *(const i32x4*)&Ac[(wm * 64 + 32 + lcol) * BK + kb];     \
            i32x4 bv0 = *(const i32x4*)&Bc[(wn * 64 +  0 + lcol) * BK + kb];     \
            i32x4 bv1 = *(const i32x4*)&Bc[(wn * 64 + 32 + lcol) * BK + kb];     \
            iacc[0][0] = __builtin_amdgcn_mfma_i32_32x32x32_i8(av0, bv0, SEED(0,0), 0, 0, 0); \
            iacc[0][1] = __builtin_amdgcn_mfma_i32_32x32x32_i8(av0, bv1, SEED(0,1), 0, 0, 0); \
            iacc[1][0] = __builtin_amdgcn_mfma_i32_32x32x32_i8(av1, bv0, SEED(1,0), 0, 0, 0); \
            iacc[1][1] = __builtin_amdgcn_mfma_i32_32x32x32_i8(av1, bv1, SEED(1,1), 0, 0, 0); \
        }
#define SEEDZ(i, j) z16
#define SEEDA(i, j) iacc[i][j]
        if (pf) issue8<0>(st, An, tid);
        KSPHASE(0, SEEDZ)
        if (pf) packw8<0>(Anx, st, tid);
        if (pf) issue8<2>(st, An, tid);
        KSPHASE(1, SEEDA)
        if (pf) packw8<2>(Anx, st, tid);
        if (pf) issue8<0>(st, Wn, tid);
        KSPHASE(2, SEEDA)
        if (pf) packw8<0>(Bnx, st, tid);
        if (pf) issue8<2>(st, Wn, tid);
        KSPHASE(3, SEEDA)
#pragma unroll
        for (int i = 0; i < 16; ++i) {
            facc[0][0][i] += (float)iacc[0][0][i] * sc0;
            facc[0][1][i] += (float)iacc[0][1][i] * sc1;
            facc[1][0][i] += (float)iacc[1][0][i] * sc0;
            facc[1][1][i] += (float)iacc[1][1][i] * sc1;
        }
        if (pf) packw8<2>(Bnx, st, tid);
        __syncthreads();
        c ^= 1;
#undef KSPHASE
#undef SEEDZ
#undef SEEDA
    }

    const float* ptok  = per_tok  + e * MEt + tm * BM;
    const float* pchan = per_chan + (size_t)e * ND;
    float* og = out + (size_t)(e * MEt + tm * BM) * ND + tn * BN;
#pragma unroll
    for (int fm = 0; fm < 2; ++fm) {
        int mb = wm * 64 + fm * 32;
#pragma unroll
        for (int fn = 0; fn < 2; ++fn) {
            int nn = wn * 64 + fn * 32 + lcol;
            float pc = pchan[tn * BN + nn];
#pragma unroll
            for (int rg = 0; rg < 16; ++rg) {
                int mr = mb + (rg & 3) + 8 * (rg >> 2) + 4 * lhi;
                float pt = ptok[mr];
                og[(size_t)mr * ND + nn] = facc[fm][fn][rg] * pt * pc;
            }
        }
    }
}

extern "C" void kernel_launch(void* const* d_in, const int* in_sizes, int n_in,
                              void* d_out, int out_size, void* d_ws, size_t ws_size,
                              hipStream_t stream) {
    const int*   a_q = (const int*)d_in[0];
    const int*   w_q = (const int*)d_in[1];
    const float* pt  = (const float*)d_in[2];
    const float* pc  = (const float*)d_in[3];
    const float* wg  = (const float*)d_in[4];
    float* out = (float*)d_out;

    const size_t A8_BYTES = (size_t)NE * MEt * KD;      // 16 MiB
    const size_t W8_BYTES = (size_t)NE * ND * KD;       // 32 MiB
    if (ws_size >= A8_BYTES + W8_BYTES) {
        unsigned char* a8 = (unsigned char*)d_ws;
        unsigned char* w8 = a8 + A8_BYTES;
        const int total_chunks = (int)((A8_BYTES + W8_BYTES) / 16);
        w4a8_prepack<<<dim3((total_chunks + 255) / 256), dim3(256), 0, stream>>>(a_q, w_q, a8, w8);
        w4a8_gemm_pp<<<dim3(1024), dim3(256), 0, stream>>>(a8, w8, pt, pc, wg, out);
    } else {
        w4a8_moe_gemm_fused<<<dim3(1024), dim3(256), 0, stream>>>(a_q, w_q, pt, pc, wg, out);
    }
}